// Round 10
// baseline (884.184 us; speedup 1.0000x reference)
//
#include <hip/hip_runtime.h>
#include <cmath>

typedef float f32x4 __attribute__((ext_vector_type(4)));
typedef short short8 __attribute__((ext_vector_type(8)));

#define N_POINTS 524288
#define TMASK 0x7FFFFu   // T_MAX-1, hashed levels all have size 2^19
#define NCELLS 32768     // 32^3 Morton cells

struct HashCfg { int res[16]; int off[16]; unsigned hashed_mask; int total; };

// ---- ws layout (bytes) ----
#define S0_OFF   0
#define S1_OFF   1024
#define S2_OFF   2048
#define W2L_OFF  3328
#define B0_OFF   4608
#define B1_OFF   (B0_OFF + 49152)
#define B2_OFF   (B1_OFF + 131072)
// B2 now 17 nt-tiles (tile 16 = [w2last, zeros]): 17*8*512*2 = 139264 B
#define TBF_OFF  (B2_OFF + 139264)   // bf16x2 table copy (~24.5 MB); sort arrays after

__device__ inline unsigned short f2bf(float f){
  unsigned u = __float_as_uint(f);
  u = (u + 0x7FFFu + ((u >> 16) & 1u)) >> 16;
  return (unsigned short)u;
}
__device__ inline float bf2f(unsigned short h){
  return __uint_as_float(((unsigned)h) << 16);
}
__device__ inline float softplus100_fast(float x){
  float y = 100.f * x;
  return 0.01f * (fmaxf(y, 0.f) + __logf(1.f + __expf(-fabsf(y))));
}
__device__ inline unsigned morton5(unsigned cx, unsigned cy, unsigned cz){
  unsigned k = 0;
  #pragma unroll
  for (int b = 0; b < 5; b++){
    k |= ((cx >> b) & 1u) << (3*b)
       | ((cy >> b) & 1u) << (3*b + 1)
       | ((cz >> b) & 1u) << (3*b + 2);
  }
  return k;
}

// ---- precompute 1: weight-norm row scales ----
__global__ void scale_kernel(const float* __restrict__ v0, const float* __restrict__ g0,
                             const float* __restrict__ v1, const float* __restrict__ g1,
                             const float* __restrict__ v2, const float* __restrict__ g2,
                             char* __restrict__ ws){
  int r = blockIdx.x * 256 + threadIdx.x;
  if (r < 256){
    float s = 0.f;
    for (int k = 0; k < 71; k++){ float t = v0[r*71+k]; s += t*t; }
    ((float*)(ws + S0_OFF))[r] = g0[r] / sqrtf(s);
  } else if (r < 512){
    int o = r - 256; float s = 0.f;
    for (int k = 0; k < 256; k++){ float t = v1[o*256+k]; s += t*t; }
    ((float*)(ws + S1_OFF))[o] = g1[o] / sqrtf(s);
  } else if (r < 769){
    int o = r - 512; float s = 0.f;
    for (int k = 0; k < 256; k++){ float t = v2[o*256+k]; s += t*t; }
    ((float*)(ws + S2_OFF))[o] = g2[o] / sqrtf(s);
  }
}

// ---- precompute 2: pack normalized weights into MFMA fragment order (bf16) ----
// element (nt,kt,l,j): k = kt*32 + (l>>4)*8 + j ; col = nt*16 + (l&15); value = Wn[col][k]
// B2 has 17 nt tiles; tile 16 col 256 = w2last (the 257th output row), cols 257..271 = 0.
__global__ void pack_kernel(const float* __restrict__ v0, const float* __restrict__ v1,
                            const float* __restrict__ v2, char* __restrict__ ws){
  int i = blockIdx.x * 256 + threadIdx.x;
  const float* s0 = (const float*)(ws + S0_OFF);
  const float* s1 = (const float*)(ws + S1_OFF);
  const float* s2 = (const float*)(ws + S2_OFF);
  if (i < 24576){                        // B0: 16 nt * 3 kt * 512
    int j = i & 7, l = (i >> 3) & 63, q = i >> 9;
    int kt = q % 3, nt = q / 3;
    int k = kt*32 + (l >> 4)*8 + j, col = nt*16 + (l & 15);
    float v = (k < 71) ? v0[col*71 + k] * s0[col] : 0.f;
    ((unsigned short*)(ws + B0_OFF))[i] = f2bf(v);
  } else if (i < 90112){                 // B1: 16 nt * 8 kt * 512
    int e = i - 24576;
    int j = e & 7, l = (e >> 3) & 63, q = e >> 9;
    int kt = q & 7, nt = q >> 3;
    int k = kt*32 + (l >> 4)*8 + j, col = nt*16 + (l & 15);
    ((unsigned short*)(ws + B1_OFF))[e] = f2bf(v1[col*256 + k] * s1[col]);
  } else if (i < 159744){                // B2: 17 nt * 8 kt * 512
    int e = i - 90112;
    int j = e & 7, l = (e >> 3) & 63, q = e >> 9;
    int kt = q & 7, nt = q >> 3;
    int k = kt*32 + (l >> 4)*8 + j, col = nt*16 + (l & 15);
    float v;
    if (col < 256)       v = v2[col*256 + k] * s2[col];
    else if (col == 256) v = v2[256*256 + k] * s2[256];
    else                 v = 0.f;
    ((unsigned short*)(ws + B2_OFF))[e] = f2bf(v);
  } else if (i < 160000){                // w2 last row, fp32 (legacy slot, unused)
    int k = i - 159744;
    ((float*)(ws + W2L_OFF))[k] = v2[256*256 + k] * s2[256];
  }
}

// ---- precompute 3: table f32 -> packed bf16x2 ----
__global__ void tconv_kernel(const float* __restrict__ table, char* __restrict__ ws, int total){
  int i = blockIdx.x * 256 + threadIdx.x;
  if (i < total){
    float2 v = ((const float2*)table)[i];
    ((unsigned*)(ws + TBF_OFF))[i] = ((unsigned)f2bf(v.x)) | (((unsigned)f2bf(v.y)) << 16);
  }
}

// ---- sort passes ----
__global__ void hist_kernel(const float* __restrict__ xin,
                            unsigned* __restrict__ hist, unsigned* __restrict__ keys){
  int i = blockIdx.x * 256 + threadIdx.x;
  float x0 = xin[i*3], x1 = xin[i*3+1], x2 = xin[i*3+2];
  unsigned cx = min(31u, (unsigned)(x0 * 32.f));
  unsigned cy = min(31u, (unsigned)(x1 * 32.f));
  unsigned cz = min(31u, (unsigned)(x2 * 32.f));
  unsigned k = morton5(cx, cy, cz);
  keys[i] = k;
  atomicAdd(&hist[k], 1u);
}

__global__ __launch_bounds__(1024) void scan_kernel(unsigned* __restrict__ hist){
  __shared__ unsigned sdata[1024];
  int t = threadIdx.x;
  unsigned loc[32];
  unsigned s = 0;
  #pragma unroll
  for (int k = 0; k < 32; k++){ loc[k] = hist[t*32 + k]; s += loc[k]; }
  sdata[t] = s;
  __syncthreads();
  for (int d = 1; d < 1024; d <<= 1){
    unsigned v = (t >= d) ? sdata[t - d] : 0u;
    __syncthreads();
    sdata[t] += v;
    __syncthreads();
  }
  unsigned run = (t == 0) ? 0u : sdata[t - 1];
  #pragma unroll
  for (int k = 0; k < 32; k++){ unsigned c = loc[k]; hist[t*32 + k] = run; run += c; }
}

__global__ void scatter_kernel(const float* __restrict__ xin,
                               const unsigned* __restrict__ keys,
                               unsigned* __restrict__ hist, int* __restrict__ perm,
                               float* __restrict__ sx){
  int i = blockIdx.x * 256 + threadIdx.x;
  unsigned k = keys[i];
  unsigned r = atomicAdd(&hist[k], 1u);
  perm[r] = i;
  sx[r*3]   = xin[i*3];
  sx[r*3+1] = xin[i*3+1];
  sx[r*3+2] = xin[i*3+2];
}

// ============================================================================
// Fused v8: fused7 minus instructions — col-256 folded into layer-2 MFMA
// (17th B2 tile), colsc pass and 2 barriers removed, hash strength-reduced.
// ============================================================================
template<int USEBF>
__global__ __launch_bounds__(512, 4) void fused8(
    const float* __restrict__ xin, const float* __restrict__ table,
    char* __restrict__ ws, const int* __restrict__ perm, const float* __restrict__ sx,
    const float* __restrict__ b0, const float* __restrict__ b1, const float* __restrict__ b2,
    float* __restrict__ out, HashCfg cfg)
{
  __shared__ unsigned short buf[128 * 256];  // swizzled: elem(row,col) at col^((row&7)<<3)
  __shared__ int pids_sh[128];

  const int tid  = threadIdx.x;
  const int p    = tid & 127;        // point for gather/feature phase
  const int lgrp = tid >> 7;         // 0..3: level-group / trig role
  const int grp  = tid >> 6;         // wave id 0..7
  const int wm   = grp >> 2;         // row-tile (0..1): rows wm*64..+64
  const int wn   = grp & 3;          // col-tile (0..3): cols wn*64..+64
  const int l    = tid & 63;
  const int lr   = l & 15;
  const int lh   = l >> 4;
  // bijective XCD swizzle over 4096 blocks (8 * 512)
  const int lb   = (blockIdx.x & 7) * 512 + (blockIdx.x >> 3);
  const int base_idx = lb * 128;

  const unsigned* __restrict__ tbf = (const unsigned*)(ws + TBF_OFF);
  const short8* B0p = (const short8*)(ws + B0_OFF);
  const short8* B1p = (const short8*)(ws + B1_OFF);
  const short8* B2p = (const short8*)(ws + B2_OFF);

  auto stB = [&](int row, int col, float v){
    buf[row*256 + (col ^ ((row & 7) << 3))] = f2bf(v);
  };
  auto ldB = [&](int row, int kb) -> short8 {
    return *(const short8*)&buf[row*256 + (kb ^ ((row & 7) << 3))];
  };

  if (tid < 128) pids_sh[tid] = perm ? perm[base_idx + tid] : (base_idx + tid);

  // ---------- phase E: gather (4 levels/thread) + trig, phase-local regs ----------
  {
    const float* src = sx ? sx : xin;
    const float X = src[(base_idx + p)*3];
    const float Y = src[(base_idx + p)*3 + 1];
    const float Z = src[(base_idx + p)*3 + 2];

    unsigned vb[4][8];
    float2   vf2[4][8];   // f32-table fallback only (dead when USEBF=1)

    #pragma unroll
    for (int ii = 0; ii < 4; ii++){
      int lev = lgrp*4 + ii;
      int res = cfg.res[lev];
      float scl = (float)(res - 1);
      unsigned cx0 = (unsigned)floorf(X*scl);
      unsigned cy0 = (unsigned)floorf(Y*scl);
      unsigned cz0 = (unsigned)floorf(Z*scl);
      unsigned r1 = (unsigned)(res + 1);
      bool hl = (cfg.hashed_mask >> lev) & 1;
      unsigned base = (unsigned)cfg.off[lev];
      // strength-reduced hash / grid index bases
      unsigned hy0 = cy0 * 2654435761u, hy1 = hy0 + 2654435761u;
      unsigned hz0 = cz0 * 805459861u,  hz1 = hz0 + 805459861u;
      unsigned n00 = cx0 + cy0 * r1 + cz0 * r1 * r1;
      #pragma unroll
      for (int c = 0; c < 8; c++){
        unsigned bx = (c >> 2) & 1, by = (c >> 1) & 1, bz = c & 1;
        unsigned hidx = hl ? (((cx0 + bx) ^ (by ? hy1 : hy0) ^ (bz ? hz1 : hz0)) & TMASK)
                           : (n00 + bx + by * r1 + bz * r1 * r1);
        if constexpr (USEBF) vb[ii][c]  = tbf[base + hidx];
        else                 vf2[ii][c] = *(const float2*)(table + (size_t)(base + hidx) * 2u);
      }
    }

    // trig / input / K-pad overlaps gather latency
    if (lgrp < 3){
      float xv[3] = {X, Y, Z};
      #pragma unroll
      for (int fi = 0; fi < 2; fi++){
        int f = lgrp*2 + fi;
        float fr = (float)(1 << f);
        #pragma unroll
        for (int d = 0; d < 3; d++){
          float ang = xv[d] * fr;
          stB(p, 3 + f*6 + d,     __sinf(ang));
          stB(p, 3 + f*6 + 3 + d, __cosf(ang));
        }
      }
    } else {
      stB(p, 0, X); stB(p, 1, Y); stB(p, 2, Z);
      #pragma unroll
      for (int c = 71; c < 96; c++)
        buf[p*256 + (c ^ ((p & 7) << 3))] = 0;
    }

    // consume
    #pragma unroll
    for (int ii = 0; ii < 4; ii++){
      int lev = lgrp*4 + ii;
      int res = cfg.res[lev];
      float scl = (float)(res - 1);
      float px = X*scl, py = Y*scl, pz = Z*scl;
      float wx = px - floorf(px), wy = py - floorf(py), wz = pz - floorf(pz);
      float f0 = 0.f, f1 = 0.f;
      #pragma unroll
      for (int c = 0; c < 8; c++){
        unsigned bx = (c >> 2) & 1, by = (c >> 1) & 1, bz = c & 1;
        float w = (bx ? wx : 1.f - wx) * (by ? wy : 1.f - wy) * (bz ? wz : 1.f - wz);
        if constexpr (USEBF){
          unsigned u = vb[ii][c];
          f0 += w * __uint_as_float(u << 16);
          f1 += w * __uint_as_float(u & 0xffff0000u);
        } else {
          f0 += w * vf2[ii][c].x;
          f1 += w * vf2[ii][c].y;
        }
      }
      stB(p, 39 + 2*lev, f0);
      stB(p, 40 + 2*lev, f1);
    }
  }
  __syncthreads();   // BAR 1: features visible

  // ---------- hidden layers ----------
  auto hidden_layer = [&](const short8* Bp, int nkt, const float* bias){
    f32x4 acc[4][4];
    #pragma unroll
    for (int a = 0; a < 4; a++)
      #pragma unroll
      for (int b = 0; b < 4; b++) acc[a][b] = (f32x4){0.f,0.f,0.f,0.f};
    __builtin_amdgcn_s_setprio(1);
    for (int kt = 0; kt < nkt; kt++){
      short8 af[4];
      #pragma unroll
      for (int mt = 0; mt < 4; mt++) af[mt] = ldB(wm*64 + mt*16 + lr, kt*32 + lh*8);
      #pragma unroll
      for (int nt = 0; nt < 4; nt++){
        short8 bf = Bp[((wn*4 + nt)*nkt + kt)*64 + l];
        #pragma unroll
        for (int mt = 0; mt < 4; mt++)
          acc[mt][nt] = __builtin_amdgcn_mfma_f32_16x16x32_bf16(af[mt], bf, acc[mt][nt], 0, 0, 0);
      }
    }
    __builtin_amdgcn_s_setprio(0);
    __syncthreads();   // all buf reads complete before overwrite
    float bb[4];
    #pragma unroll
    for (int nt = 0; nt < 4; nt++) bb[nt] = bias[wn*64 + nt*16 + lr];
    #pragma unroll
    for (int mt = 0; mt < 4; mt++)
      #pragma unroll
      for (int nt = 0; nt < 4; nt++){
        int c = wn*64 + nt*16 + lr;
        #pragma unroll
        for (int j = 0; j < 4; j++)
          stB(wm*64 + mt*16 + lh*4 + j, c, softplus100_fast(acc[mt][nt][j] + bb[nt]));
      }
  };

  hidden_layer(B0p, 3, b0);   // BAR 2 inside
  __syncthreads();            // BAR 3: h1 visible
  hidden_layer(B1p, 8, b1);   // BAR 4 inside
  __syncthreads();            // BAR 5: h2 visible

  { // ----- layer 2 (+17th tile for col 256 on wn==3 waves) + direct stores -----
    f32x4 acc[4][4];
    f32x4 acc4[4];             // extra tile accum (cols 256..271), wn==3 only
    #pragma unroll
    for (int a = 0; a < 4; a++){
      #pragma unroll
      for (int b = 0; b < 4; b++) acc[a][b] = (f32x4){0.f,0.f,0.f,0.f};
      acc4[a] = (f32x4){0.f,0.f,0.f,0.f};
    }
    __builtin_amdgcn_s_setprio(1);
    for (int kt = 0; kt < 8; kt++){
      short8 af[4];
      #pragma unroll
      for (int mt = 0; mt < 4; mt++) af[mt] = ldB(wm*64 + mt*16 + lr, kt*32 + lh*8);
      #pragma unroll
      for (int nt = 0; nt < 4; nt++){
        short8 bf = B2p[((wn*4 + nt)*8 + kt)*64 + l];
        #pragma unroll
        for (int mt = 0; mt < 4; mt++)
          acc[mt][nt] = __builtin_amdgcn_mfma_f32_16x16x32_bf16(af[mt], bf, acc[mt][nt], 0, 0, 0);
      }
      if (wn == 3){
        short8 bf = B2p[(16*8 + kt)*64 + l];
        #pragma unroll
        for (int mt = 0; mt < 4; mt++)
          acc4[mt] = __builtin_amdgcn_mfma_f32_16x16x32_bf16(af[mt], bf, acc4[mt], 0, 0, 0);
      }
    }
    __builtin_amdgcn_s_setprio(0);
    // no barrier: stores depend only on acc + pids_sh (stable since start)
    float bb[4];
    #pragma unroll
    for (int nt = 0; nt < 4; nt++) bb[nt] = b2[wn*64 + nt*16 + lr];
    #pragma unroll
    for (int mt = 0; mt < 4; mt++)
      #pragma unroll
      for (int nt = 0; nt < 4; nt++){
        int c = wn*64 + nt*16 + lr;
        #pragma unroll
        for (int j = 0; j < 4; j++)
          out[(size_t)pids_sh[wm*64 + mt*16 + lh*4 + j]*257 + c] = acc[mt][nt][j] + bb[nt];
      }
    if (wn == 3 && lr == 0){
      float blast = b2[256];
      #pragma unroll
      for (int mt = 0; mt < 4; mt++)
        #pragma unroll
        for (int j = 0; j < 4; j++)
          out[(size_t)pids_sh[wm*64 + mt*16 + lh*4 + j]*257 + 256] = acc4[mt][j] + blast;
    }
  }
}

// ---- host: replicate reference's double-precision level config exactly ----
static HashCfg make_cfg(){
  HashCfg c;
  double pls = exp2(log2(2048.0 / 16.0) / 15.0);
  long long off = 0;
  unsigned mask = 0;
  for (int l = 0; l < 16; l++){
    int r = (int)ceil(16.0 * pow(pls, (double)l));
    c.res[l] = r;
    c.off[l] = (int)off;
    double n3 = (double)(r + 1) * (double)(r + 1) * (double)(r + 1);
    long long size;
    if (n3 > 524288.0){ mask |= (1u << l); }
    size = (long long)(ceil(n3 / 8.0) * 8.0);
    if (size > 524288) size = 524288;
    off += size;
  }
  c.hashed_mask = mask;
  c.total = (int)off;
  return c;
}

extern "C" void kernel_launch(void* const* d_in, const int* in_sizes, int n_in,
                              void* d_out, int out_size, void* d_ws, size_t ws_size,
                              hipStream_t stream) {
  const float* x     = (const float*)d_in[0];
  const float* table = (const float*)d_in[1];
  const float* v0 = (const float*)d_in[2];
  const float* g0 = (const float*)d_in[3];
  const float* b0 = (const float*)d_in[4];
  const float* v1 = (const float*)d_in[5];
  const float* g1 = (const float*)d_in[6];
  const float* b1 = (const float*)d_in[7];
  const float* v2 = (const float*)d_in[8];
  const float* g2 = (const float*)d_in[9];
  const float* b2 = (const float*)d_in[10];
  float* out = (float*)d_out;
  char* ws = (char*)d_ws;

  HashCfg cfg = make_cfg();
  size_t tbf_bytes = (size_t)cfg.total * 4u;
  size_t hist_off  = (TBF_OFF + tbf_bytes + 255) & ~(size_t)255;
  size_t keys_off  = hist_off + (size_t)NCELLS * 4;
  size_t perm_off  = keys_off + (size_t)N_POINTS * 4;
  size_t sx_off    = perm_off + (size_t)N_POINTS * 4;
  size_t need_sort = sx_off + (size_t)N_POINTS * 12;
  size_t need_bf   = TBF_OFF + tbf_bytes;

  hipLaunchKernelGGL(scale_kernel, dim3(4), dim3(256), 0, stream, v0, g0, v1, g1, v2, g2, ws);
  hipLaunchKernelGGL(pack_kernel, dim3(625), dim3(256), 0, stream, v0, v1, v2, ws);

  const int nblk = N_POINTS / 128;   // 4096

  if (ws_size >= need_sort){
    unsigned* hist = (unsigned*)(ws + hist_off);
    unsigned* keys = (unsigned*)(ws + keys_off);
    int*      perm = (int*)(ws + perm_off);
    float*    sx   = (float*)(ws + sx_off);
    hipMemsetAsync(hist, 0, (size_t)NCELLS * 4, stream);
    hipLaunchKernelGGL(tconv_kernel, dim3((cfg.total + 255) / 256), dim3(256), 0, stream,
                       table, ws, cfg.total);
    hipLaunchKernelGGL(hist_kernel, dim3(N_POINTS / 256), dim3(256), 0, stream, x, hist, keys);
    hipLaunchKernelGGL(scan_kernel, dim3(1), dim3(1024), 0, stream, hist);
    hipLaunchKernelGGL(scatter_kernel, dim3(N_POINTS / 256), dim3(256), 0, stream,
                       x, keys, hist, perm, sx);
    hipLaunchKernelGGL((fused8<1>), dim3(nblk), dim3(512), 0, stream,
                       x, table, ws, perm, sx, b0, b1, b2, out, cfg);
  } else if (ws_size >= need_bf){
    hipLaunchKernelGGL(tconv_kernel, dim3((cfg.total + 255) / 256), dim3(256), 0, stream,
                       table, ws, cfg.total);
    hipLaunchKernelGGL((fused8<1>), dim3(nblk), dim3(512), 0, stream,
                       x, table, ws, (const int*)nullptr, (const float*)nullptr,
                       b0, b1, b2, out, cfg);
  } else {
    hipLaunchKernelGGL((fused8<0>), dim3(nblk), dim3(512), 0, stream,
                       x, table, ws, (const int*)nullptr, (const float*)nullptr,
                       b0, b1, b2, out, cfg);
  }
}

// Round 11
// 828.848 us; speedup vs baseline: 1.0668x; 1.0668x over previous
//
#include <hip/hip_runtime.h>
#include <cmath>

typedef float f32x4 __attribute__((ext_vector_type(4)));
typedef short short8 __attribute__((ext_vector_type(8)));

#define N_POINTS 524288
#define TMASK 0x7FFFFu   // T_MAX-1, hashed levels all have size 2^19
#define NCELLS 32768     // 32^3 Morton cells
#define P2H 2654435761u
#define P3H 805459861u
#define RGN_CAP 1024     // LDS region arena entries (levels 0-5)

struct HashCfg { int res[16]; int off[16]; unsigned hashed_mask; int total; };

// ---- ws layout (bytes) ----
#define S0_OFF   0
#define S1_OFF   1024
#define S2_OFF   2048
#define W2L_OFF  3328
#define B0_OFF   4608
#define B1_OFF   (B0_OFF + 49152)
#define B2_OFF   (B1_OFF + 131072)
#define TBF_OFF  (B2_OFF + 131072)   // bf16x2 table copy (~24.5 MB); sort arrays after

__device__ inline unsigned short f2bf(float f){
  unsigned u = __float_as_uint(f);
  u = (u + 0x7FFFu + ((u >> 16) & 1u)) >> 16;
  return (unsigned short)u;
}
__device__ inline float bf2f(unsigned short h){
  return __uint_as_float(((unsigned)h) << 16);
}
__device__ inline float softplus100_fast(float x){
  float y = 100.f * x;
  return 0.01f * (fmaxf(y, 0.f) + __logf(1.f + __expf(-fabsf(y))));
}
__device__ inline unsigned morton5(unsigned cx, unsigned cy, unsigned cz){
  unsigned k = 0;
  #pragma unroll
  for (int b = 0; b < 5; b++){
    k |= ((cx >> b) & 1u) << (3*b)
       | ((cy >> b) & 1u) << (3*b + 1)
       | ((cz >> b) & 1u) << (3*b + 2);
  }
  return k;
}

// ---- precompute 1: weight-norm row scales ----
__global__ void scale_kernel(const float* __restrict__ v0, const float* __restrict__ g0,
                             const float* __restrict__ v1, const float* __restrict__ g1,
                             const float* __restrict__ v2, const float* __restrict__ g2,
                             char* __restrict__ ws){
  int r = blockIdx.x * 256 + threadIdx.x;
  if (r < 256){
    float s = 0.f;
    for (int k = 0; k < 71; k++){ float t = v0[r*71+k]; s += t*t; }
    ((float*)(ws + S0_OFF))[r] = g0[r] / sqrtf(s);
  } else if (r < 512){
    int o = r - 256; float s = 0.f;
    for (int k = 0; k < 256; k++){ float t = v1[o*256+k]; s += t*t; }
    ((float*)(ws + S1_OFF))[o] = g1[o] / sqrtf(s);
  } else if (r < 769){
    int o = r - 512; float s = 0.f;
    for (int k = 0; k < 256; k++){ float t = v2[o*256+k]; s += t*t; }
    ((float*)(ws + S2_OFF))[o] = g2[o] / sqrtf(s);
  }
}

// ---- precompute 2: pack normalized weights into MFMA B-fragment order (bf16) ----
__global__ void pack_kernel(const float* __restrict__ v0, const float* __restrict__ v1,
                            const float* __restrict__ v2, char* __restrict__ ws){
  int i = blockIdx.x * 256 + threadIdx.x;
  const float* s0 = (const float*)(ws + S0_OFF);
  const float* s1 = (const float*)(ws + S1_OFF);
  const float* s2 = (const float*)(ws + S2_OFF);
  if (i < 24576){
    int j = i & 7, l = (i >> 3) & 63, q = i >> 9;
    int kt = q % 3, nt = q / 3;
    int k = kt*32 + (l >> 4)*8 + j, col = nt*16 + (l & 15);
    float v = (k < 71) ? v0[col*71 + k] * s0[col] : 0.f;
    ((unsigned short*)(ws + B0_OFF))[i] = f2bf(v);
  } else if (i < 90112){
    int e = i - 24576;
    int j = e & 7, l = (e >> 3) & 63, q = e >> 9;
    int kt = q & 7, nt = q >> 3;
    int k = kt*32 + (l >> 4)*8 + j, col = nt*16 + (l & 15);
    ((unsigned short*)(ws + B1_OFF))[e] = f2bf(v1[col*256 + k] * s1[col]);
  } else if (i < 155648){
    int e = i - 90112;
    int j = e & 7, l = (e >> 3) & 63, q = e >> 9;
    int kt = q & 7, nt = q >> 3;
    int k = kt*32 + (l >> 4)*8 + j, col = nt*16 + (l & 15);
    ((unsigned short*)(ws + B2_OFF))[e] = f2bf(v2[col*256 + k] * s2[col]);
  } else if (i < 155904){
    int k = i - 155648;
    ((float*)(ws + W2L_OFF))[k] = v2[256*256 + k] * s2[256];
  }
}

// ---- precompute 3: table f32 -> packed bf16x2 ----
__global__ void tconv_kernel(const float* __restrict__ table, char* __restrict__ ws, int total){
  int i = blockIdx.x * 256 + threadIdx.x;
  if (i < total){
    float2 v = ((const float2*)table)[i];
    ((unsigned*)(ws + TBF_OFF))[i] = ((unsigned)f2bf(v.x)) | (((unsigned)f2bf(v.y)) << 16);
  }
}

// ---- sort passes ----
__global__ void hist_kernel(const float* __restrict__ xin,
                            unsigned* __restrict__ hist, unsigned* __restrict__ keys){
  int i = blockIdx.x * 256 + threadIdx.x;
  float x0 = xin[i*3], x1 = xin[i*3+1], x2 = xin[i*3+2];
  unsigned cx = min(31u, (unsigned)(x0 * 32.f));
  unsigned cy = min(31u, (unsigned)(x1 * 32.f));
  unsigned cz = min(31u, (unsigned)(x2 * 32.f));
  unsigned k = morton5(cx, cy, cz);
  keys[i] = k;
  atomicAdd(&hist[k], 1u);
}

__global__ __launch_bounds__(1024) void scan_kernel(unsigned* __restrict__ hist){
  __shared__ unsigned sdata[1024];
  int t = threadIdx.x;
  unsigned loc[32];
  unsigned s = 0;
  #pragma unroll
  for (int k = 0; k < 32; k++){ loc[k] = hist[t*32 + k]; s += loc[k]; }
  sdata[t] = s;
  __syncthreads();
  for (int d = 1; d < 1024; d <<= 1){
    unsigned v = (t >= d) ? sdata[t - d] : 0u;
    __syncthreads();
    sdata[t] += v;
    __syncthreads();
  }
  unsigned run = (t == 0) ? 0u : sdata[t - 1];
  #pragma unroll
  for (int k = 0; k < 32; k++){ unsigned c = loc[k]; hist[t*32 + k] = run; run += c; }
}

__global__ void scatter_kernel(const float* __restrict__ xin,
                               const unsigned* __restrict__ keys,
                               unsigned* __restrict__ hist, int* __restrict__ perm,
                               float* __restrict__ sx){
  int i = blockIdx.x * 256 + threadIdx.x;
  unsigned k = keys[i];
  unsigned r = atomicAdd(&hist[k], 1u);
  perm[r] = i;
  sx[r*3]   = xin[i*3];
  sx[r*3+1] = xin[i*3+1];
  sx[r*3+2] = xin[i*3+2];
}

// ============================================================================
// Fused v9 = fused7 + LDS region dedup for levels 0-5.
// Coarse-level table entries for the block's bbox are gathered ONCE into a
// 4KB LDS arena; per-point corner lookups become LDS reads. Cuts per-block
// VMEM gather requests ~32% (the per-CU request-rate wall).
// ============================================================================
template<int USEBF>
__global__ __launch_bounds__(512, 4) void fused9(
    const float* __restrict__ xin, const float* __restrict__ table,
    char* __restrict__ ws, const int* __restrict__ perm, const float* __restrict__ sx,
    const float* __restrict__ b0, const float* __restrict__ b1, const float* __restrict__ b2,
    float* __restrict__ out, HashCfg cfg)
{
  __shared__ unsigned short buf[128 * 256];  // swizzled: elem(row,col) at col^((row&7)<<3)
  __shared__ float colsc[4][128];
  __shared__ int pids_sh[128];
  __shared__ unsigned rgn[RGN_CAP];          // region arena (levels 0-5)
  __shared__ int rprm[6][10];                // ox,oy,oz,dx,dxy,off,ok,invdx,invdxy,cnt
  __shared__ int bboxi[6];                   // minx,maxx,miny,maxy,minz,maxz (float-as-int)

  const int tid  = threadIdx.x;
  const int p    = tid & 127;
  const int lgrp = tid >> 7;         // 0..3
  const int grp  = tid >> 6;         // wave id 0..7
  const int wm   = grp >> 2;
  const int wn   = grp & 3;
  const int l    = tid & 63;
  const int lr   = l & 15;
  const int lh   = l >> 4;
  const int lb   = (blockIdx.x & 7) * 512 + (blockIdx.x >> 3);
  const int base_idx = lb * 128;

  const unsigned* __restrict__ tbf = (const unsigned*)(ws + TBF_OFF);
  const short8* B0p = (const short8*)(ws + B0_OFF);
  const short8* B1p = (const short8*)(ws + B1_OFF);
  const short8* B2p = (const short8*)(ws + B2_OFF);
  const float* w2l = (const float*)(ws + W2L_OFF);

  auto stB = [&](int row, int col, float v){
    buf[row*256 + (col ^ ((row & 7) << 3))] = f2bf(v);
  };
  auto ldB = [&](int row, int kb) -> short8 {
    return *(const short8*)&buf[row*256 + (kb ^ ((row & 7) << 3))];
  };

  if (tid < 128) pids_sh[tid] = perm ? perm[base_idx + tid] : (base_idx + tid);
  if (tid < 6)   bboxi[tid] = (tid & 1) ? 0 : 0x7f7fffff;   // even=min(init big), odd=max(init 0)

  const float* src = sx ? sx : xin;
  const float X = src[(base_idx + p)*3];
  const float Y = src[(base_idx + p)*3 + 1];
  const float Z = src[(base_idx + p)*3 + 2];
  __syncthreads();    // bbox init + pids visible

  // ---- bbox: wave shfl-reduce then one atomic per wave ----
  {
    float mnx = X, mxx = X, mny = Y, mxy = Y, mnz = Z, mxz = Z;
    #pragma unroll
    for (int m = 1; m < 64; m <<= 1){
      mnx = fminf(mnx, __shfl_xor(mnx, m)); mxx = fmaxf(mxx, __shfl_xor(mxx, m));
      mny = fminf(mny, __shfl_xor(mny, m)); mxy = fmaxf(mxy, __shfl_xor(mxy, m));
      mnz = fminf(mnz, __shfl_xor(mnz, m)); mxz = fmaxf(mxz, __shfl_xor(mxz, m));
    }
    if (l == 0){   // positive floats: int compare == float compare
      atomicMin(&bboxi[0], __float_as_int(mnx)); atomicMax(&bboxi[1], __float_as_int(mxx));
      atomicMin(&bboxi[2], __float_as_int(mny)); atomicMax(&bboxi[3], __float_as_int(mxy));
      atomicMin(&bboxi[4], __float_as_int(mnz)); atomicMax(&bboxi[5], __float_as_int(mxz));
    }
  }
  __syncthreads();    // bbox final

  // ---- region params (thread 0) ----
  if (tid == 0){
    float mnx = __int_as_float(bboxi[0]), mxx = __int_as_float(bboxi[1]);
    float mny = __int_as_float(bboxi[2]), mxy = __int_as_float(bboxi[3]);
    float mnz = __int_as_float(bboxi[4]), mxz = __int_as_float(bboxi[5]);
    int off = 0;
    for (int lev = 0; lev < 6; lev++){
      float scl = (float)(cfg.res[lev] - 1);
      int x0 = (int)floorf(mnx*scl), x1 = (int)floorf(mxx*scl);
      int y0 = (int)floorf(mny*scl), y1 = (int)floorf(mxy*scl);
      int z0 = (int)floorf(mnz*scl), z1 = (int)floorf(mxz*scl);
      int dx = x1 - x0 + 2, dy = y1 - y0 + 2, dz = z1 - z0 + 2;
      int cnt = dx * dy * dz;
      int ok = (off + cnt <= RGN_CAP) ? 1 : 0;
      rprm[lev][0] = x0; rprm[lev][1] = y0; rprm[lev][2] = z0;
      rprm[lev][3] = dx; rprm[lev][4] = dx*dy; rprm[lev][5] = off; rprm[lev][6] = ok;
      rprm[lev][7] = __float_as_int(1.0f / (float)dx);
      rprm[lev][8] = __float_as_int(1.0f / (float)(dx*dy));
      rprm[lev][9] = cnt;
      if (ok) off += cnt;
    }
  }
  __syncthreads();    // rprm visible

  // ---- direct gathers for levels >= 6 (phase-local registers) ----
  unsigned vb[4][8];
  float2   vf2[4][8];
  #pragma unroll
  for (int ii = 0; ii < 4; ii++){
    int lev = lgrp*4 + ii;
    if (lev >= 6){
      int res = cfg.res[lev];
      float scl = (float)(res - 1);
      unsigned cx0 = (unsigned)floorf(X*scl);
      unsigned cy0 = (unsigned)floorf(Y*scl);
      unsigned cz0 = (unsigned)floorf(Z*scl);
      unsigned r1 = (unsigned)(res + 1);
      bool hl = (cfg.hashed_mask >> lev) & 1;
      unsigned base = (unsigned)cfg.off[lev];
      #pragma unroll
      for (int c = 0; c < 8; c++){
        unsigned bx = (c >> 2) & 1, by = (c >> 1) & 1, bz = c & 1;
        unsigned cx = cx0 + bx, cy = cy0 + by, cz = cz0 + bz;
        unsigned hidx = hl ? ((cx ^ (cy * P2H) ^ (cz * P3H)) & TMASK)
                           : (cx + cy * r1 + cz * r1 * r1);
        if constexpr (USEBF) vb[ii][c]  = tbf[base + hidx];
        else                 vf2[ii][c] = *(const float2*)(table + (size_t)(base + hidx) * 2u);
      }
    }
  }

  // ---- cooperative region load (levels 0-5) ----
  if constexpr (USEBF){
    for (int lev = 0; lev < 6; lev++){
      if (!rprm[lev][6]) continue;
      int dx  = rprm[lev][3], dxy = rprm[lev][4], off = rprm[lev][5], cnt = rprm[lev][9];
      float invdx  = __int_as_float(rprm[lev][7]);
      float invdxy = __int_as_float(rprm[lev][8]);
      int ox = rprm[lev][0], oy = rprm[lev][1], oz = rprm[lev][2];
      int res = cfg.res[lev];
      unsigned r1 = (unsigned)(res + 1);
      bool hl = (cfg.hashed_mask >> lev) & 1;
      unsigned base = (unsigned)cfg.off[lev];
      for (int e = tid; e < cnt; e += 512){
        int k = (int)((float)e * invdxy);
        if ((k+1)*dxy <= e) k++;
        if (k*dxy > e) k--;
        int rem = e - k*dxy;
        int j = (int)((float)rem * invdx);
        if ((j+1)*dx <= rem) j++;
        if (j*dx > rem) j--;
        int i = rem - j*dx;
        unsigned gx = (unsigned)(ox + i), gy = (unsigned)(oy + j), gz = (unsigned)(oz + k);
        unsigned hidx = hl ? ((gx ^ (gy * P2H) ^ (gz * P3H)) & TMASK)
                           : (gx + gy * r1 + gz * r1 * r1);
        rgn[off + e] = tbf[base + hidx];
      }
    }
  }

  // ---- trig / input / K-pad (overlaps outstanding loads) ----
  if (lgrp < 3){
    float xv[3] = {X, Y, Z};
    #pragma unroll
    for (int fi = 0; fi < 2; fi++){
      int f = lgrp*2 + fi;
      float fr = (float)(1 << f);
      #pragma unroll
      for (int d = 0; d < 3; d++){
        float ang = xv[d] * fr;
        stB(p, 3 + f*6 + d,     __sinf(ang));
        stB(p, 3 + f*6 + 3 + d, __cosf(ang));
      }
    }
  } else {
    stB(p, 0, X); stB(p, 1, Y); stB(p, 2, Z);
    #pragma unroll
    for (int c = 71; c < 96; c++)
      buf[p*256 + (c ^ ((p & 7) << 3))] = 0;
  }
  __syncthreads();    // region arena visible

  // ---- consume: features ----
  #pragma unroll
  for (int ii = 0; ii < 4; ii++){
    int lev = lgrp*4 + ii;
    int res = cfg.res[lev];
    float scl = (float)(res - 1);
    float px = X*scl, py = Y*scl, pz = Z*scl;
    float fx = floorf(px), fy = floorf(py), fz = floorf(pz);
    float wx = px - fx, wy = py - fy, wz = pz - fz;
    float f0 = 0.f, f1 = 0.f;
    if (lev < 6 && USEBF && rprm[lev][6]){
      int dx  = rprm[lev][3], dxy = rprm[lev][4], off = rprm[lev][5];
      int bidx = off + ((int)fx - rprm[lev][0]) + ((int)fy - rprm[lev][1])*dx
               + ((int)fz - rprm[lev][2])*dxy;
      #pragma unroll
      for (int c = 0; c < 8; c++){
        int bx = (c >> 2) & 1, by = (c >> 1) & 1, bz = c & 1;
        float w = (bx ? wx : 1.f - wx) * (by ? wy : 1.f - wy) * (bz ? wz : 1.f - wz);
        unsigned u = rgn[bidx + bx + by*dx + bz*dxy];
        f0 += w * __uint_as_float(u << 16);
        f1 += w * __uint_as_float(u & 0xffff0000u);
      }
    } else if (lev < 6){
      // fallback: direct gather (arena overflow or f32 path)
      unsigned cx0 = (unsigned)fx, cy0 = (unsigned)fy, cz0 = (unsigned)fz;
      unsigned r1 = (unsigned)(res + 1);
      bool hl = (cfg.hashed_mask >> lev) & 1;
      unsigned base = (unsigned)cfg.off[lev];
      #pragma unroll
      for (int c = 0; c < 8; c++){
        unsigned bx = (c >> 2) & 1, by = (c >> 1) & 1, bz = c & 1;
        unsigned cx = cx0 + bx, cy = cy0 + by, cz = cz0 + bz;
        unsigned hidx = hl ? ((cx ^ (cy * P2H) ^ (cz * P3H)) & TMASK)
                           : (cx + cy * r1 + cz * r1 * r1);
        float w = (bx ? wx : 1.f - wx) * (by ? wy : 1.f - wy) * (bz ? wz : 1.f - wz);
        if constexpr (USEBF){
          unsigned u = tbf[base + hidx];
          f0 += w * __uint_as_float(u << 16);
          f1 += w * __uint_as_float(u & 0xffff0000u);
        } else {
          float2 fv = *(const float2*)(table + (size_t)(base + hidx) * 2u);
          f0 += w * fv.x; f1 += w * fv.y;
        }
      }
    } else {
      #pragma unroll
      for (int c = 0; c < 8; c++){
        unsigned bx = (c >> 2) & 1, by = (c >> 1) & 1, bz = c & 1;
        float w = (bx ? wx : 1.f - wx) * (by ? wy : 1.f - wy) * (bz ? wz : 1.f - wz);
        if constexpr (USEBF){
          unsigned u = vb[ii][c];
          f0 += w * __uint_as_float(u << 16);
          f1 += w * __uint_as_float(u & 0xffff0000u);
        } else {
          f0 += w * vf2[ii][c].x;
          f1 += w * vf2[ii][c].y;
        }
      }
    }
    stB(p, 39 + 2*lev, f0);
    stB(p, 40 + 2*lev, f1);
  }
  __syncthreads();    // features visible

  // ---------- MFMA layers (identical to fused7) ----------
  auto hidden_layer = [&](const short8* Bp, int nkt, const float* bias){
    f32x4 acc[4][4];
    #pragma unroll
    for (int a = 0; a < 4; a++)
      #pragma unroll
      for (int b = 0; b < 4; b++) acc[a][b] = (f32x4){0.f,0.f,0.f,0.f};
    __builtin_amdgcn_s_setprio(1);
    for (int kt = 0; kt < nkt; kt++){
      short8 af[4];
      #pragma unroll
      for (int mt = 0; mt < 4; mt++) af[mt] = ldB(wm*64 + mt*16 + lr, kt*32 + lh*8);
      #pragma unroll
      for (int nt = 0; nt < 4; nt++){
        short8 bf = Bp[((wn*4 + nt)*nkt + kt)*64 + l];
        #pragma unroll
        for (int mt = 0; mt < 4; mt++)
          acc[mt][nt] = __builtin_amdgcn_mfma_f32_16x16x32_bf16(af[mt], bf, acc[mt][nt], 0, 0, 0);
      }
    }
    __builtin_amdgcn_s_setprio(0);
    __syncthreads();
    float bb[4];
    #pragma unroll
    for (int nt = 0; nt < 4; nt++) bb[nt] = bias[wn*64 + nt*16 + lr];
    #pragma unroll
    for (int mt = 0; mt < 4; mt++)
      #pragma unroll
      for (int nt = 0; nt < 4; nt++){
        int c = wn*64 + nt*16 + lr;
        #pragma unroll
        for (int j = 0; j < 4; j++)
          stB(wm*64 + mt*16 + lh*4 + j, c, softplus100_fast(acc[mt][nt][j] + bb[nt]));
      }
  };

  hidden_layer(B0p, 3, b0);
  __syncthreads();
  hidden_layer(B1p, 8, b1);
  __syncthreads();

  {
    int row = tid & 127, ch = tid >> 7;
    float s = 0.f;
    #pragma unroll
    for (int q = 0; q < 8; q++){
      short8 h = ldB(row, ch*64 + q*8);
      #pragma unroll
      for (int j = 0; j < 8; j++)
        s += bf2f((unsigned short)h[j]) * w2l[ch*64 + q*8 + j];
    }
    colsc[ch][row] = s;
  }

  {
    f32x4 acc[4][4];
    #pragma unroll
    for (int a = 0; a < 4; a++)
      #pragma unroll
      for (int b = 0; b < 4; b++) acc[a][b] = (f32x4){0.f,0.f,0.f,0.f};
    __builtin_amdgcn_s_setprio(1);
    for (int kt = 0; kt < 8; kt++){
      short8 af[4];
      #pragma unroll
      for (int mt = 0; mt < 4; mt++) af[mt] = ldB(wm*64 + mt*16 + lr, kt*32 + lh*8);
      #pragma unroll
      for (int nt = 0; nt < 4; nt++){
        short8 bf = B2p[((wn*4 + nt)*8 + kt)*64 + l];
        #pragma unroll
        for (int mt = 0; mt < 4; mt++)
          acc[mt][nt] = __builtin_amdgcn_mfma_f32_16x16x32_bf16(af[mt], bf, acc[mt][nt], 0, 0, 0);
      }
    }
    __builtin_amdgcn_s_setprio(0);
    __syncthreads();
    float bb[4];
    #pragma unroll
    for (int nt = 0; nt < 4; nt++) bb[nt] = b2[wn*64 + nt*16 + lr];
    #pragma unroll
    for (int mt = 0; mt < 4; mt++)
      #pragma unroll
      for (int nt = 0; nt < 4; nt++){
        int c = wn*64 + nt*16 + lr;
        #pragma unroll
        for (int j = 0; j < 4; j++)
          out[(size_t)pids_sh[wm*64 + mt*16 + lh*4 + j]*257 + c] = acc[mt][nt][j] + bb[nt];
      }
    if (tid < 128)
      out[(size_t)pids_sh[tid]*257 + 256] =
        colsc[0][tid] + colsc[1][tid] + colsc[2][tid] + colsc[3][tid] + b2[256];
  }
}

// ---- host: replicate reference's double-precision level config exactly ----
static HashCfg make_cfg(){
  HashCfg c;
  double pls = exp2(log2(2048.0 / 16.0) / 15.0);
  long long off = 0;
  unsigned mask = 0;
  for (int l = 0; l < 16; l++){
    int r = (int)ceil(16.0 * pow(pls, (double)l));
    c.res[l] = r;
    c.off[l] = (int)off;
    double n3 = (double)(r + 1) * (double)(r + 1) * (double)(r + 1);
    long long size;
    if (n3 > 524288.0){ mask |= (1u << l); }
    size = (long long)(ceil(n3 / 8.0) * 8.0);
    if (size > 524288) size = 524288;
    off += size;
  }
  c.hashed_mask = mask;
  c.total = (int)off;
  return c;
}

extern "C" void kernel_launch(void* const* d_in, const int* in_sizes, int n_in,
                              void* d_out, int out_size, void* d_ws, size_t ws_size,
                              hipStream_t stream) {
  const float* x     = (const float*)d_in[0];
  const float* table = (const float*)d_in[1];
  const float* v0 = (const float*)d_in[2];
  const float* g0 = (const float*)d_in[3];
  const float* b0 = (const float*)d_in[4];
  const float* v1 = (const float*)d_in[5];
  const float* g1 = (const float*)d_in[6];
  const float* b1 = (const float*)d_in[7];
  const float* v2 = (const float*)d_in[8];
  const float* g2 = (const float*)d_in[9];
  const float* b2 = (const float*)d_in[10];
  float* out = (float*)d_out;
  char* ws = (char*)d_ws;

  HashCfg cfg = make_cfg();
  size_t tbf_bytes = (size_t)cfg.total * 4u;
  size_t hist_off  = (TBF_OFF + tbf_bytes + 255) & ~(size_t)255;
  size_t keys_off  = hist_off + (size_t)NCELLS * 4;
  size_t perm_off  = keys_off + (size_t)N_POINTS * 4;
  size_t sx_off    = perm_off + (size_t)N_POINTS * 4;
  size_t need_sort = sx_off + (size_t)N_POINTS * 12;
  size_t need_bf   = TBF_OFF + tbf_bytes;

  hipLaunchKernelGGL(scale_kernel, dim3(4), dim3(256), 0, stream, v0, g0, v1, g1, v2, g2, ws);
  hipLaunchKernelGGL(pack_kernel, dim3(609), dim3(256), 0, stream, v0, v1, v2, ws);

  const int nblk = N_POINTS / 128;   // 4096

  if (ws_size >= need_sort){
    unsigned* hist = (unsigned*)(ws + hist_off);
    unsigned* keys = (unsigned*)(ws + keys_off);
    int*      perm = (int*)(ws + perm_off);
    float*    sx   = (float*)(ws + sx_off);
    hipMemsetAsync(hist, 0, (size_t)NCELLS * 4, stream);
    hipLaunchKernelGGL(tconv_kernel, dim3((cfg.total + 255) / 256), dim3(256), 0, stream,
                       table, ws, cfg.total);
    hipLaunchKernelGGL(hist_kernel, dim3(N_POINTS / 256), dim3(256), 0, stream, x, hist, keys);
    hipLaunchKernelGGL(scan_kernel, dim3(1), dim3(1024), 0, stream, hist);
    hipLaunchKernelGGL(scatter_kernel, dim3(N_POINTS / 256), dim3(256), 0, stream,
                       x, keys, hist, perm, sx);
    hipLaunchKernelGGL((fused9<1>), dim3(nblk), dim3(512), 0, stream,
                       x, table, ws, perm, sx, b0, b1, b2, out, cfg);
  } else if (ws_size >= need_bf){
    hipLaunchKernelGGL(tconv_kernel, dim3((cfg.total + 255) / 256), dim3(256), 0, stream,
                       table, ws, cfg.total);
    hipLaunchKernelGGL((fused9<1>), dim3(nblk), dim3(512), 0, stream,
                       x, table, ws, (const int*)nullptr, (const float*)nullptr,
                       b0, b1, b2, out, cfg);
  } else {
    hipLaunchKernelGGL((fused9<0>), dim3(nblk), dim3(512), 0, stream,
                       x, table, ws, (const int*)nullptr, (const float*)nullptr,
                       b0, b1, b2, out, cfg);
  }
}

// Round 12
// 786.740 us; speedup vs baseline: 1.1239x; 1.0535x over previous
//
#include <hip/hip_runtime.h>
#include <cmath>

typedef float f32x4 __attribute__((ext_vector_type(4)));
typedef short short8 __attribute__((ext_vector_type(8)));

#define N_POINTS 524288
#define TMASK 0x7FFFFu   // T_MAX-1, hashed levels all have size 2^19
#define NCELLS 32768     // 32^3 Morton cells

struct HashCfg { int res[16]; int off[16]; unsigned hashed_mask; int total; };

// ---- ws layout (bytes) ----
#define S0_OFF   0
#define S1_OFF   1024
#define S2_OFF   2048
#define W2L_OFF  3328
#define B0_OFF   4608
#define B1_OFF   (B0_OFF + 49152)
#define B2_OFF   (B1_OFF + 131072)
#define TBF_OFF  (B2_OFF + 131072)   // bf16x2 table copy (~24.5 MB); sort arrays after

__device__ inline unsigned short f2bf(float f){
  unsigned u = __float_as_uint(f);
  u = (u + 0x7FFFu + ((u >> 16) & 1u)) >> 16;
  return (unsigned short)u;
}
__device__ inline float bf2f(unsigned short h){
  return __uint_as_float(((unsigned)h) << 16);
}
__device__ inline float softplus100_fast(float x){
  float y = 100.f * x;
  return 0.01f * (fmaxf(y, 0.f) + __logf(1.f + __expf(-fabsf(y))));
}
__device__ inline unsigned morton5(unsigned cx, unsigned cy, unsigned cz){
  unsigned k = 0;
  #pragma unroll
  for (int b = 0; b < 5; b++){
    k |= ((cx >> b) & 1u) << (3*b)
       | ((cy >> b) & 1u) << (3*b + 1)
       | ((cz >> b) & 1u) << (3*b + 2);
  }
  return k;
}

// ---- precompute 1: weight-norm row scales ----
__global__ void scale_kernel(const float* __restrict__ v0, const float* __restrict__ g0,
                             const float* __restrict__ v1, const float* __restrict__ g1,
                             const float* __restrict__ v2, const float* __restrict__ g2,
                             char* __restrict__ ws){
  int r = blockIdx.x * 256 + threadIdx.x;
  if (r < 256){
    float s = 0.f;
    for (int k = 0; k < 71; k++){ float t = v0[r*71+k]; s += t*t; }
    ((float*)(ws + S0_OFF))[r] = g0[r] / sqrtf(s);
  } else if (r < 512){
    int o = r - 256; float s = 0.f;
    for (int k = 0; k < 256; k++){ float t = v1[o*256+k]; s += t*t; }
    ((float*)(ws + S1_OFF))[o] = g1[o] / sqrtf(s);
  } else if (r < 769){
    int o = r - 512; float s = 0.f;
    for (int k = 0; k < 256; k++){ float t = v2[o*256+k]; s += t*t; }
    ((float*)(ws + S2_OFF))[o] = g2[o] / sqrtf(s);
  }
}

// ---- precompute 2: pack normalized weights into MFMA B-fragment order (bf16) ----
__global__ void pack_kernel(const float* __restrict__ v0, const float* __restrict__ v1,
                            const float* __restrict__ v2, char* __restrict__ ws){
  int i = blockIdx.x * 256 + threadIdx.x;
  const float* s0 = (const float*)(ws + S0_OFF);
  const float* s1 = (const float*)(ws + S1_OFF);
  const float* s2 = (const float*)(ws + S2_OFF);
  if (i < 24576){
    int j = i & 7, l = (i >> 3) & 63, q = i >> 9;
    int kt = q % 3, nt = q / 3;
    int k = kt*32 + (l >> 4)*8 + j, col = nt*16 + (l & 15);
    float v = (k < 71) ? v0[col*71 + k] * s0[col] : 0.f;
    ((unsigned short*)(ws + B0_OFF))[i] = f2bf(v);
  } else if (i < 90112){
    int e = i - 24576;
    int j = e & 7, l = (e >> 3) & 63, q = e >> 9;
    int kt = q & 7, nt = q >> 3;
    int k = kt*32 + (l >> 4)*8 + j, col = nt*16 + (l & 15);
    ((unsigned short*)(ws + B1_OFF))[e] = f2bf(v1[col*256 + k] * s1[col]);
  } else if (i < 155648){
    int e = i - 90112;
    int j = e & 7, l = (e >> 3) & 63, q = e >> 9;
    int kt = q & 7, nt = q >> 3;
    int k = kt*32 + (l >> 4)*8 + j, col = nt*16 + (l & 15);
    ((unsigned short*)(ws + B2_OFF))[e] = f2bf(v2[col*256 + k] * s2[col]);
  } else if (i < 155904){
    int k = i - 155648;
    ((float*)(ws + W2L_OFF))[k] = v2[256*256 + k] * s2[256];
  }
}

// ---- precompute 3: table f32 -> packed bf16x2 ----
__global__ void tconv_kernel(const float* __restrict__ table, char* __restrict__ ws, int total){
  int i = blockIdx.x * 256 + threadIdx.x;
  if (i < total){
    float2 v = ((const float2*)table)[i];
    ((unsigned*)(ws + TBF_OFF))[i] = ((unsigned)f2bf(v.x)) | (((unsigned)f2bf(v.y)) << 16);
  }
}

// ---- sort passes ----
__global__ void hist_kernel(const float* __restrict__ xin,
                            unsigned* __restrict__ hist, unsigned* __restrict__ keys){
  int i = blockIdx.x * 256 + threadIdx.x;
  float x0 = xin[i*3], x1 = xin[i*3+1], x2 = xin[i*3+2];
  unsigned cx = min(31u, (unsigned)(x0 * 32.f));
  unsigned cy = min(31u, (unsigned)(x1 * 32.f));
  unsigned cz = min(31u, (unsigned)(x2 * 32.f));
  unsigned k = morton5(cx, cy, cz);
  keys[i] = k;
  atomicAdd(&hist[k], 1u);
}

__global__ __launch_bounds__(1024) void scan_kernel(unsigned* __restrict__ hist){
  __shared__ unsigned sdata[1024];
  int t = threadIdx.x;
  unsigned loc[32];
  unsigned s = 0;
  #pragma unroll
  for (int k = 0; k < 32; k++){ loc[k] = hist[t*32 + k]; s += loc[k]; }
  sdata[t] = s;
  __syncthreads();
  for (int d = 1; d < 1024; d <<= 1){
    unsigned v = (t >= d) ? sdata[t - d] : 0u;
    __syncthreads();
    sdata[t] += v;
    __syncthreads();
  }
  unsigned run = (t == 0) ? 0u : sdata[t - 1];
  #pragma unroll
  for (int k = 0; k < 32; k++){ unsigned c = loc[k]; hist[t*32 + k] = run; run += c; }
}

__global__ void scatter_kernel(const float* __restrict__ xin,
                               const unsigned* __restrict__ keys,
                               unsigned* __restrict__ hist, int* __restrict__ perm,
                               float* __restrict__ sx){
  int i = blockIdx.x * 256 + threadIdx.x;
  unsigned k = keys[i];
  unsigned r = atomicAdd(&hist[k], 1u);
  perm[r] = i;
  sx[r*3]   = xin[i*3];
  sx[r*3+1] = xin[i*3+1];
  sx[r*3+2] = xin[i*3+2];
}

// ============================================================================
// Fused v7 (best measured): 512 threads, 128 sorted points per block.
// Phase-local gathers (regs dead before MFMA), 8 waves in 2M x 4N grid.
// ============================================================================
template<int USEBF>
__global__ __launch_bounds__(512, 4) void fused7(
    const float* __restrict__ xin, const float* __restrict__ table,
    char* __restrict__ ws, const int* __restrict__ perm, const float* __restrict__ sx,
    const float* __restrict__ b0, const float* __restrict__ b1, const float* __restrict__ b2,
    float* __restrict__ out, HashCfg cfg)
{
  __shared__ unsigned short buf[128 * 256];  // swizzled: elem(row,col) at col^((row&7)<<3)
  __shared__ float colsc[4][128];
  __shared__ int pids_sh[128];

  const int tid  = threadIdx.x;
  const int p    = tid & 127;        // point for gather/feature phase
  const int lgrp = tid >> 7;         // 0..3: level-group / trig role
  const int grp  = tid >> 6;         // wave id 0..7
  const int wm   = grp >> 2;         // row-tile (0..1): rows wm*64..+64
  const int wn   = grp & 3;          // col-tile (0..3): cols wn*64..+64
  const int l    = tid & 63;
  const int lr   = l & 15;
  const int lh   = l >> 4;
  // bijective XCD swizzle over 4096 blocks (8 * 512)
  const int lb   = (blockIdx.x & 7) * 512 + (blockIdx.x >> 3);
  const int base_idx = lb * 128;

  const unsigned* __restrict__ tbf = (const unsigned*)(ws + TBF_OFF);
  const short8* B0p = (const short8*)(ws + B0_OFF);
  const short8* B1p = (const short8*)(ws + B1_OFF);
  const short8* B2p = (const short8*)(ws + B2_OFF);
  const float* w2l = (const float*)(ws + W2L_OFF);

  auto stB = [&](int row, int col, float v){
    buf[row*256 + (col ^ ((row & 7) << 3))] = f2bf(v);
  };
  auto ldB = [&](int row, int kb) -> short8 {
    return *(const short8*)&buf[row*256 + (kb ^ ((row & 7) << 3))];
  };

  if (tid < 128) pids_sh[tid] = perm ? perm[base_idx + tid] : (base_idx + tid);

  // ---------- phase E: gather (4 levels/thread) + trig, phase-local regs ----------
  {
    const float* src = sx ? sx : xin;
    const float X = src[(base_idx + p)*3];
    const float Y = src[(base_idx + p)*3 + 1];
    const float Z = src[(base_idx + p)*3 + 2];

    unsigned vb[4][8];
    float2   vf2[4][8];   // f32-table fallback only (dead when USEBF=1)

    #pragma unroll
    for (int ii = 0; ii < 4; ii++){
      int lev = lgrp*4 + ii;
      int res = cfg.res[lev];
      float scl = (float)(res - 1);
      unsigned cx0 = (unsigned)floorf(X*scl);
      unsigned cy0 = (unsigned)floorf(Y*scl);
      unsigned cz0 = (unsigned)floorf(Z*scl);
      unsigned r1 = (unsigned)(res + 1);
      bool hl = (cfg.hashed_mask >> lev) & 1;
      unsigned base = (unsigned)cfg.off[lev];
      #pragma unroll
      for (int c = 0; c < 8; c++){
        unsigned bx = (c >> 2) & 1, by = (c >> 1) & 1, bz = c & 1;
        unsigned cx = cx0 + bx, cy = cy0 + by, cz = cz0 + bz;
        unsigned hidx = hl ? ((cx ^ (cy * 2654435761u) ^ (cz * 805459861u)) & TMASK)
                           : (cx + cy * r1 + cz * r1 * r1);
        if constexpr (USEBF) vb[ii][c]  = tbf[base + hidx];
        else                 vf2[ii][c] = *(const float2*)(table + (size_t)(base + hidx) * 2u);
      }
    }

    // trig / input / K-pad overlaps gather latency
    if (lgrp < 3){
      float xv[3] = {X, Y, Z};
      #pragma unroll
      for (int fi = 0; fi < 2; fi++){
        int f = lgrp*2 + fi;
        float fr = (float)(1 << f);
        #pragma unroll
        for (int d = 0; d < 3; d++){
          float ang = xv[d] * fr;
          stB(p, 3 + f*6 + d,     __sinf(ang));
          stB(p, 3 + f*6 + 3 + d, __cosf(ang));
        }
      }
    } else {
      stB(p, 0, X); stB(p, 1, Y); stB(p, 2, Z);
      #pragma unroll
      for (int c = 71; c < 96; c++)
        buf[p*256 + (c ^ ((p & 7) << 3))] = 0;
    }

    // consume
    #pragma unroll
    for (int ii = 0; ii < 4; ii++){
      int lev = lgrp*4 + ii;
      int res = cfg.res[lev];
      float scl = (float)(res - 1);
      float px = X*scl, py = Y*scl, pz = Z*scl;
      float wx = px - floorf(px), wy = py - floorf(py), wz = pz - floorf(pz);
      float f0 = 0.f, f1 = 0.f;
      #pragma unroll
      for (int c = 0; c < 8; c++){
        unsigned bx = (c >> 2) & 1, by = (c >> 1) & 1, bz = c & 1;
        float w = (bx ? wx : 1.f - wx) * (by ? wy : 1.f - wy) * (bz ? wz : 1.f - wz);
        if constexpr (USEBF){
          unsigned u = vb[ii][c];
          f0 += w * __uint_as_float(u << 16);
          f1 += w * __uint_as_float(u & 0xffff0000u);
        } else {
          f0 += w * vf2[ii][c].x;
          f1 += w * vf2[ii][c].y;
        }
      }
      stB(p, 39 + 2*lev, f0);
      stB(p, 40 + 2*lev, f1);
    }
  }
  __syncthreads();

  // ---------- MFMA layers ----------
  auto hidden_layer = [&](const short8* Bp, int nkt, const float* bias){
    f32x4 acc[4][4];
    #pragma unroll
    for (int a = 0; a < 4; a++)
      #pragma unroll
      for (int b = 0; b < 4; b++) acc[a][b] = (f32x4){0.f,0.f,0.f,0.f};
    __builtin_amdgcn_s_setprio(1);
    for (int kt = 0; kt < nkt; kt++){
      short8 af[4];
      #pragma unroll
      for (int mt = 0; mt < 4; mt++) af[mt] = ldB(wm*64 + mt*16 + lr, kt*32 + lh*8);
      #pragma unroll
      for (int nt = 0; nt < 4; nt++){
        short8 bf = Bp[((wn*4 + nt)*nkt + kt)*64 + l];
        #pragma unroll
        for (int mt = 0; mt < 4; mt++)
          acc[mt][nt] = __builtin_amdgcn_mfma_f32_16x16x32_bf16(af[mt], bf, acc[mt][nt], 0, 0, 0);
      }
    }
    __builtin_amdgcn_s_setprio(0);
    __syncthreads();   // all buf reads complete before overwrite
    float bb[4];
    #pragma unroll
    for (int nt = 0; nt < 4; nt++) bb[nt] = bias[wn*64 + nt*16 + lr];
    #pragma unroll
    for (int mt = 0; mt < 4; mt++)
      #pragma unroll
      for (int nt = 0; nt < 4; nt++){
        int c = wn*64 + nt*16 + lr;
        #pragma unroll
        for (int j = 0; j < 4; j++)
          stB(wm*64 + mt*16 + lh*4 + j, c, softplus100_fast(acc[mt][nt][j] + bb[nt]));
      }
  };

  hidden_layer(B0p, 3, b0);
  __syncthreads();
  hidden_layer(B1p, 8, b1);
  __syncthreads();

  // last-col partials: thread handles row (tid&127), col chunk (tid>>7)*64..+64
  {
    int row = tid & 127, ch = tid >> 7;
    float s = 0.f;
    #pragma unroll
    for (int q = 0; q < 8; q++){
      short8 h = ldB(row, ch*64 + q*8);
      #pragma unroll
      for (int j = 0; j < 8; j++)
        s += bf2f((unsigned short)h[j]) * w2l[ch*64 + q*8 + j];
    }
    colsc[ch][row] = s;
  }

  { // ----- layer 2 + scattered stores -----
    f32x4 acc[4][4];
    #pragma unroll
    for (int a = 0; a < 4; a++)
      #pragma unroll
      for (int b = 0; b < 4; b++) acc[a][b] = (f32x4){0.f,0.f,0.f,0.f};
    __builtin_amdgcn_s_setprio(1);
    for (int kt = 0; kt < 8; kt++){
      short8 af[4];
      #pragma unroll
      for (int mt = 0; mt < 4; mt++) af[mt] = ldB(wm*64 + mt*16 + lr, kt*32 + lh*8);
      #pragma unroll
      for (int nt = 0; nt < 4; nt++){
        short8 bf = B2p[((wn*4 + nt)*8 + kt)*64 + l];
        #pragma unroll
        for (int mt = 0; mt < 4; mt++)
          acc[mt][nt] = __builtin_amdgcn_mfma_f32_16x16x32_bf16(af[mt], bf, acc[mt][nt], 0, 0, 0);
      }
    }
    __builtin_amdgcn_s_setprio(0);
    __syncthreads();   // colsc partials visible
    float bb[4];
    #pragma unroll
    for (int nt = 0; nt < 4; nt++) bb[nt] = b2[wn*64 + nt*16 + lr];
    #pragma unroll
    for (int mt = 0; mt < 4; mt++)
      #pragma unroll
      for (int nt = 0; nt < 4; nt++){
        int c = wn*64 + nt*16 + lr;
        #pragma unroll
        for (int j = 0; j < 4; j++)
          out[(size_t)pids_sh[wm*64 + mt*16 + lh*4 + j]*257 + c] = acc[mt][nt][j] + bb[nt];
      }
    if (tid < 128)
      out[(size_t)pids_sh[tid]*257 + 256] =
        colsc[0][tid] + colsc[1][tid] + colsc[2][tid] + colsc[3][tid] + b2[256];
  }
}

// ---- host: replicate reference's double-precision level config exactly ----
static HashCfg make_cfg(){
  HashCfg c;
  double pls = exp2(log2(2048.0 / 16.0) / 15.0);
  long long off = 0;
  unsigned mask = 0;
  for (int l = 0; l < 16; l++){
    int r = (int)ceil(16.0 * pow(pls, (double)l));
    c.res[l] = r;
    c.off[l] = (int)off;
    double n3 = (double)(r + 1) * (double)(r + 1) * (double)(r + 1);
    long long size;
    if (n3 > 524288.0){ mask |= (1u << l); }
    size = (long long)(ceil(n3 / 8.0) * 8.0);
    if (size > 524288) size = 524288;
    off += size;
  }
  c.hashed_mask = mask;
  c.total = (int)off;
  return c;
}

extern "C" void kernel_launch(void* const* d_in, const int* in_sizes, int n_in,
                              void* d_out, int out_size, void* d_ws, size_t ws_size,
                              hipStream_t stream) {
  const float* x     = (const float*)d_in[0];
  const float* table = (const float*)d_in[1];
  const float* v0 = (const float*)d_in[2];
  const float* g0 = (const float*)d_in[3];
  const float* b0 = (const float*)d_in[4];
  const float* v1 = (const float*)d_in[5];
  const float* g1 = (const float*)d_in[6];
  const float* b1 = (const float*)d_in[7];
  const float* v2 = (const float*)d_in[8];
  const float* g2 = (const float*)d_in[9];
  const float* b2 = (const float*)d_in[10];
  float* out = (float*)d_out;
  char* ws = (char*)d_ws;

  HashCfg cfg = make_cfg();
  size_t tbf_bytes = (size_t)cfg.total * 4u;
  size_t hist_off  = (TBF_OFF + tbf_bytes + 255) & ~(size_t)255;
  size_t keys_off  = hist_off + (size_t)NCELLS * 4;
  size_t perm_off  = keys_off + (size_t)N_POINTS * 4;
  size_t sx_off    = perm_off + (size_t)N_POINTS * 4;
  size_t need_sort = sx_off + (size_t)N_POINTS * 12;
  size_t need_bf   = TBF_OFF + tbf_bytes;

  hipLaunchKernelGGL(scale_kernel, dim3(4), dim3(256), 0, stream, v0, g0, v1, g1, v2, g2, ws);
  hipLaunchKernelGGL(pack_kernel, dim3(609), dim3(256), 0, stream, v0, v1, v2, ws);

  const int nblk = N_POINTS / 128;   // 4096

  if (ws_size >= need_sort){
    unsigned* hist = (unsigned*)(ws + hist_off);
    unsigned* keys = (unsigned*)(ws + keys_off);
    int*      perm = (int*)(ws + perm_off);
    float*    sx   = (float*)(ws + sx_off);
    hipMemsetAsync(hist, 0, (size_t)NCELLS * 4, stream);
    hipLaunchKernelGGL(tconv_kernel, dim3((cfg.total + 255) / 256), dim3(256), 0, stream,
                       table, ws, cfg.total);
    hipLaunchKernelGGL(hist_kernel, dim3(N_POINTS / 256), dim3(256), 0, stream, x, hist, keys);
    hipLaunchKernelGGL(scan_kernel, dim3(1), dim3(1024), 0, stream, hist);
    hipLaunchKernelGGL(scatter_kernel, dim3(N_POINTS / 256), dim3(256), 0, stream,
                       x, keys, hist, perm, sx);
    hipLaunchKernelGGL((fused7<1>), dim3(nblk), dim3(512), 0, stream,
                       x, table, ws, perm, sx, b0, b1, b2, out, cfg);
  } else if (ws_size >= need_bf){
    hipLaunchKernelGGL(tconv_kernel, dim3((cfg.total + 255) / 256), dim3(256), 0, stream,
                       table, ws, cfg.total);
    hipLaunchKernelGGL((fused7<1>), dim3(nblk), dim3(512), 0, stream,
                       x, table, ws, (const int*)nullptr, (const float*)nullptr,
                       b0, b1, b2, out, cfg);
  } else {
    hipLaunchKernelGGL((fused7<0>), dim3(nblk), dim3(512), 0, stream,
                       x, table, ws, (const int*)nullptr, (const float*)nullptr,
                       b0, b1, b2, out, cfg);
  }
}